// Round 3
// 508.782 us; speedup vs baseline: 1.0059x; 1.0059x over previous
//
#include <hip/hip_runtime.h>
#include <hip/hip_bf16.h>
#include <stdint.h>

// ---------------------------------------------------------------------------
// GCPNet forward (ALL I/O FLOAT32):
//   - M_vv @ V == rowsum(M_vv) (x) v0           (V is rank-1)
//   - color LSTM / mlpV / x_c are DEAD CODE     (never reach outputs)
//   - vertex LSTM is row-independent            -> persistent per-tile kernel
// R4: FUSION. rowsum fused into k_main (rs in LDS, no global roundtrip, no
// device-wide serialization between the 268MB stream and the LSTM). k_prep
// fused into k_setup grid. k_final retired via last-block ticket.
// R5: harden ticket path (threadfence + acquire loads on accg).
// R6: FIX R5 bug — V-broadcast loop wrote 64 rows/block (i<4) instead of 32
// (i<2); block 255 overran 16KB into the C output region. C rows 0..31 were
// clobbered with v0 (absmax 3.75 = max|C| over that span). One-line fix.
// ---------------------------------------------------------------------------

typedef __bf16 bf16x8 __attribute__((ext_vector_type(8)));
typedef float f32x4 __attribute__((ext_vector_type(4)));

#define EDIM 128
#define NVERT 8192
#define CNUM 512
#define NG 64
#define TSTEPS 32

// workspace byte offsets
#define WS_CNT 0u         // 1 u32   (completion ticket counter)
#define WS_V0 32768u      // 128 f32
#define WS_W1 33280u      // 512 f32  (Wih_v[:, :128] @ v0)
#define WS_BV 35328u      // 512 f32  (bih_v + bhh_v)
#define WS_ACC 37376u     // 64 f32   (per-graph vote sums)
#define WS_V0BF 37632u    // 128 bf16
#define WS_MLPC3T 38912u  // 128*512 bf16 (mlp3(C) transposed: [e][c])

__device__ __forceinline__ float bf2f(unsigned short s) {
  return __uint_as_float(((unsigned)s) << 16);
}
__device__ __forceinline__ unsigned short f2bf(float f) {
  unsigned u = __float_as_uint(f);
  u += 0x7fffu + ((u >> 16) & 1u);  // RNE
  return (unsigned short)(u >> 16);
}
__device__ __forceinline__ float sigm(float x) {
  return __builtin_amdgcn_rcpf(1.f + __expf(-x));
}
__device__ __forceinline__ float tanh_f(float x) {
  return 1.f - 2.f * __builtin_amdgcn_rcpf(1.f + __expf(2.f * x));
}
__device__ __forceinline__ f32x4 mfma16(bf16x8 a, bf16x8 b, f32x4 c) {
  return __builtin_amdgcn_mfma_f32_16x16x32_bf16(a, b, c, 0, 0, 0);
}
// load 8 consecutive f32 from global, convert to bf16x8 fragment
__device__ __forceinline__ bf16x8 ld8(const float* p) {
  float4 a = *(const float4*)p;
  float4 b = *(const float4*)(p + 4);
  bf16x8 r;
  r[0] = (__bf16)a.x; r[1] = (__bf16)a.y; r[2] = (__bf16)a.z; r[3] = (__bf16)a.w;
  r[4] = (__bf16)b.x; r[5] = (__bf16)b.y; r[6] = (__bf16)b.z; r[7] = (__bf16)b.w;
  return r;
}

// ---------------- setup: prep (block 512) + mlp3(C) (blocks 0..511) --------
__global__ __launch_bounds__(128) void k_setup(
    const float* __restrict__ C, const float* __restrict__ W,
    const float* __restrict__ B, const float* __restrict__ vw,
    const float* __restrict__ vb, const float* __restrict__ Wih,
    const float* __restrict__ bih, const float* __restrict__ bhh,
    float* __restrict__ ws, float* __restrict__ Cout) {
  __shared__ float xb[2][EDIM];
  const int t = threadIdx.x;

  if (blockIdx.x == CNUM) {
    // ---- prep: v0, w1 = Wih[:, :128] @ v0, bv, zero acc + ticket ----
    float* v0 = (float*)((char*)ws + WS_V0);
    float* w1 = (float*)((char*)ws + WS_W1);
    float* bvp = (float*)((char*)ws + WS_BV);
    float* acc = (float*)((char*)ws + WS_ACC);
    unsigned short* v0bf = (unsigned short*)((char*)ws + WS_V0BF);
    unsigned int* cnt = (unsigned int*)((char*)ws + WS_CNT);
    float v = vw[t] + vb[t];
    xb[0][t] = v;
    v0[t] = v;
    v0bf[t] = f2bf(v);
    if (t < NG) acc[t] = 0.f;
    if (t == 0) *cnt = 0u;
    __syncthreads();
#pragma unroll
    for (int gi = 0; gi < 4; gi++) {
      const int col = gi * EDIM + t;
      const float4* wr = (const float4*)(Wih + (size_t)col * 256);  // left cols
      float s = 0.f;
#pragma unroll
      for (int kc = 0; kc < 32; kc++) {
        float4 q = wr[kc];
        const float* xi = xb[0] + kc * 4;
        s += q.x * xi[0] + q.y * xi[1] + q.z * xi[2] + q.w * xi[3];
      }
      w1[col] = s;
      bvp[col] = bih[col] + bhh[col];
    }
    return;
  }

  // ---- mlp3(C) -> mlpC3^T (bf16) in ws, + C output copy ----
  unsigned short* out_t = (unsigned short*)((char*)ws + WS_MLPC3T);
  const int c = blockIdx.x, e = t;
  float cval = C[c * EDIM + e];
  xb[0][e] = cval;
  Cout[c * EDIM + e] = cval;  // output 3 (exact f32 copy)
  __syncthreads();
#pragma unroll
  for (int l = 0; l < 3; l++) {
    const float4* wrow = (const float4*)(W + ((size_t)l * EDIM + e) * EDIM);
    const float* xin = xb[l & 1];
    float s = B[l * EDIM + e];
#pragma unroll
    for (int kc = 0; kc < EDIM / 4; kc++) {
      float4 q = wrow[kc];
      const float* xi = xin + kc * 4;
      s += q.x * xi[0] + q.y * xi[1] + q.z * xi[2] + q.w * xi[3];
    }
    if (l < 2) {
      s = fmaxf(s, 0.f);
      __syncthreads();
      xb[(l + 1) & 1][e] = s;
      __syncthreads();
    } else {
      out_t[(size_t)e * CNUM + c] = f2bf(s);  // transposed for MFMA B reads
    }
  }
}

// ---------------- fused rowsum + LSTM + vote + final (256 x 512) -----------
// 8 waves/block; wave w owns cols [16w, 16w+16) of the 128-wide hidden dim.
__global__ __launch_bounds__(512, 1) void k_main(
    const float* __restrict__ Mvv, const float* __restrict__ Mvc,
    const float* __restrict__ Wih, const float* __restrict__ Whh,
    const float* __restrict__ W1, const float* __restrict__ b1,
    const float* __restrict__ W2, const float* __restrict__ b2,
    const float* __restrict__ W3, const float* __restrict__ b3,
    const int* __restrict__ slice, float* __restrict__ ws,
    float* __restrict__ out) {
  const int r0 = blockIdx.x * 32;
  const int t = threadIdx.x;
  const int w = t >> 6;
  const int lane = t & 63;
  const int quad = lane >> 4;
  const int l15 = lane & 15;
  const int nc0 = w * 16;  // wave's 16-col slice of 128

  __shared__ unsigned short Avc[32][CNUM + 8];     // M_vc tile (bf16)
  __shared__ unsigned short Tt[32][EDIM + 8];      // T = M_vc @ mlpC3
  __shared__ unsigned short hv2[2][32][EDIM + 8];  // double-buffered hidden
  __shared__ float votes[32];
  __shared__ float rs_s[32];                       // rowsums of block's rows
  __shared__ unsigned int last_s;

  const float* w1v = (const float*)((const char*)ws + WS_W1);
  const float* bvv = (const float*)((const char*)ws + WS_BV);
  float* accg = (float*)((char*)ws + WS_ACC);
  unsigned int* cnt = (unsigned int*)((char*)ws + WS_CNT);
  const unsigned short* v0bf = (const unsigned short*)((const char*)ws + WS_V0BF);
  const unsigned short* m3t = (const unsigned short*)((const char*)ws + WS_MLPC3T);

  // ---- phase 1: issue M_vc tile loads, stream-rowsum own 32 M_vv rows ----
  {
    const int row = t >> 4, c0 = t & 15;  // 16 threads/row
    // issue M_vc loads early (they drain under the M_vv stream)
    const float4* g = (const float4*)(Mvc + (size_t)(r0 + row) * CNUM);
    float4 av[8];
#pragma unroll
    for (int it = 0; it < 8; it++) av[it] = g[it * 16 + c0];

    // rowsum: 2048 float4/row, 16 threads/row -> 128 float4/thread,
    // chunked 16-deep for vmem pipelining (16 KB in flight per wave)
    const float4* mp = (const float4*)(Mvv + (size_t)(r0 + row) * NVERT) + c0;
    float s = 0.f;
#pragma unroll 1
    for (int ch = 0; ch < 8; ch++) {
      float4 q[16];
#pragma unroll
      for (int j = 0; j < 16; j++) q[j] = mp[ch * 256 + j * 16];
#pragma unroll
      for (int j = 0; j < 16; j++) s += q[j].x + q[j].y + q[j].z + q[j].w;
    }
    s += __shfl_down(s, 8, 16);
    s += __shfl_down(s, 4, 16);
    s += __shfl_down(s, 2, 16);
    s += __shfl_down(s, 1, 16);
    if (c0 == 0) rs_s[row] = s;

    // now convert the (long-drained) M_vc tile to bf16 in LDS
#pragma unroll
    for (int it = 0; it < 8; it++) {
      int c4 = it * 16 + c0;
      ushort4 h;
      h.x = f2bf(av[it].x); h.y = f2bf(av[it].y);
      h.z = f2bf(av[it].z); h.w = f2bf(av[it].w);
      *(ushort4*)&Avc[row][c4 * 4] = h;
    }
  }
  // output 2: V rows = v0 (exact f32), and init hv = v0 (bf16)
  // 32 rows x 32 float4/row = 1024 float4 -> exactly 2 passes of 512 threads
  {
    const float4* v04 = (const float4*)((const char*)ws + WS_V0);
    float4* V4 = (float4*)(out + NG);
#pragma unroll
    for (int i = 0; i < 2; i++) {
      int idx = t + i * 512;  // 0..1023
      int vr = idx >> 5, vc = idx & 31;
      V4[(size_t)(r0 + vr) * 32 + vc] = v04[vc];
    }
  }
  for (int i = t; i < 32 * EDIM; i += 512) hv2[0][i >> 7][i & 127] = v0bf[i & 127];
  __syncthreads();

  // ---- T = Avc @ mlpC3 (B from transposed mlpC3: contiguous in k) ----
  {
    f32x4 acc[2];
#pragma unroll
    for (int mt = 0; mt < 2; mt++) {
      acc[mt][0] = 0.f; acc[mt][1] = 0.f; acc[mt][2] = 0.f; acc[mt][3] = 0.f;
    }
#pragma unroll
    for (int kc = 0; kc < 16; kc++) {
      bf16x8 a0 = *(const bf16x8*)&Avc[l15][kc * 32 + quad * 8];
      bf16x8 a1 = *(const bf16x8*)&Avc[16 + l15][kc * 32 + quad * 8];
      bf16x8 b0 = *(const bf16x8*)&m3t[(size_t)(nc0 + l15) * CNUM + kc * 32 + quad * 8];
      acc[0] = mfma16(a0, b0, acc[0]);
      acc[1] = mfma16(a1, b0, acc[1]);
    }
#pragma unroll
    for (int mt = 0; mt < 2; mt++)
#pragma unroll
      for (int r = 0; r < 4; r++)
        Tt[mt * 16 + quad * 4 + r][nc0 + l15] = f2bf(acc[mt][r]);
  }
  __syncthreads();

  // ---- xg = x_v @ Wih^T + bih + bhh (loop-invariant gate preactivation) ----
  // left half of x_v is rs[i]*v0[e] -> contributes rs[i]*w1[g]
  f32x4 xg[2][4];  // [mtile][gate i,f,g,o]
  {
    float rsv[2][4];
#pragma unroll
    for (int mt = 0; mt < 2; mt++)
#pragma unroll
      for (int r = 0; r < 4; r++) rsv[mt][r] = rs_s[mt * 16 + quad * 4 + r];
#pragma unroll
    for (int gi = 0; gi < 4; gi++) {
      const int col = gi * 128 + nc0 + l15;
      const float w1c = w1v[col], bvc = bvv[col];
#pragma unroll
      for (int mt = 0; mt < 2; mt++)
#pragma unroll
        for (int r = 0; r < 4; r++) xg[mt][gi][r] = fmaf(rsv[mt][r], w1c, bvc);
    }
#pragma unroll
    for (int kc = 0; kc < 4; kc++) {
      bf16x8 a0 = *(const bf16x8*)&Tt[l15][kc * 32 + quad * 8];
      bf16x8 a1 = *(const bf16x8*)&Tt[16 + l15][kc * 32 + quad * 8];
#pragma unroll
      for (int gi = 0; gi < 4; gi++) {
        const int gcol = gi * 128 + nc0 + l15;
        bf16x8 bfr = ld8(&Wih[(size_t)gcol * 256 + 128 + kc * 32 + quad * 8]);
        xg[0][gi] = mfma16(a0, bfr, xg[0][gi]);
        xg[1][gi] = mfma16(a1, bfr, xg[1][gi]);
      }
    }
  }

  // Whh B-fragments held in registers for all 32 steps (64 VGPR)
  bf16x8 Bh[4][4];
#pragma unroll
  for (int gi = 0; gi < 4; gi++) {
    const int gcol = gi * 128 + nc0 + l15;
#pragma unroll
    for (int kc = 0; kc < 4; kc++)
      Bh[gi][kc] = ld8(&Whh[(size_t)gcol * EDIM + kc * 32 + quad * 8]);
  }

  f32x4 cv[2];
#pragma unroll
  for (int mt = 0; mt < 2; mt++) {
    cv[mt][0] = 0.f; cv[mt][1] = 0.f; cv[mt][2] = 0.f; cv[mt][3] = 0.f;
  }

  // ---- 32 LSTM steps; read buf p, write buf p^1, ONE barrier/step ----
  int p = 0;
#pragma unroll 1
  for (int step = 0; step < TSTEPS; step++) {
    bf16x8 A[2][4];
#pragma unroll
    for (int mt = 0; mt < 2; mt++)
#pragma unroll
      for (int kc = 0; kc < 4; kc++)
        A[mt][kc] = *(const bf16x8*)&hv2[p][mt * 16 + l15][kc * 32 + quad * 8];
#pragma unroll
    for (int mt = 0; mt < 2; mt++) {
      f32x4 gI = xg[mt][0], gF = xg[mt][1], gG = xg[mt][2], gO = xg[mt][3];
#pragma unroll
      for (int kc = 0; kc < 4; kc++) {
        gI = mfma16(A[mt][kc], Bh[0][kc], gI);
        gF = mfma16(A[mt][kc], Bh[1][kc], gF);
        gG = mfma16(A[mt][kc], Bh[2][kc], gG);
        gO = mfma16(A[mt][kc], Bh[3][kc], gO);
      }
#pragma unroll
      for (int r = 0; r < 4; r++) {
        float ig = sigm(gI[r]), fg = sigm(gF[r]);
        float gg = tanh_f(gG[r]), og = sigm(gO[r]);
        float c2 = fmaf(fg, cv[mt][r], ig * gg);
        cv[mt][r] = c2;
        hv2[p ^ 1][mt * 16 + quad * 4 + r][nc0 + l15] = f2bf(og * tanh_f(c2));
      }
    }
    p ^= 1;
    __syncthreads();
  }
  // after 32 steps (even), final h is in hv2[0]

  // ---- fused vote MLP: two relu layers via MFMA ----
  for (int layer = 0; layer < 2; layer++) {
    const float* Wg = layer ? W2 : W1;
    const float* bg = layer ? b2 : b1;
    bf16x8 A[2][4];
#pragma unroll
    for (int mt = 0; mt < 2; mt++)
#pragma unroll
      for (int kc = 0; kc < 4; kc++)
        A[mt][kc] = *(const bf16x8*)&hv2[0][mt * 16 + l15][kc * 32 + quad * 8];
    f32x4 acc[2];
    {
      float bb = bg[nc0 + l15];
#pragma unroll
      for (int mt = 0; mt < 2; mt++) {
        acc[mt][0] = bb; acc[mt][1] = bb; acc[mt][2] = bb; acc[mt][3] = bb;
      }
    }
#pragma unroll
    for (int kc = 0; kc < 4; kc++) {
      bf16x8 bfr = ld8(&Wg[(size_t)(nc0 + l15) * EDIM + kc * 32 + quad * 8]);
      acc[0] = mfma16(A[0][kc], bfr, acc[0]);
      acc[1] = mfma16(A[1][kc], bfr, acc[1]);
    }
    __syncthreads();  // all A reads done before overwrite
#pragma unroll
    for (int mt = 0; mt < 2; mt++)
#pragma unroll
      for (int r = 0; r < 4; r++)
        hv2[0][mt * 16 + quad * 4 + r][nc0 + l15] = f2bf(fmaxf(acc[mt][r], 0.f));
    __syncthreads();
  }

  // final vote row-dot + per-graph partial sum (block is inside one graph)
  {
    const int row = t >> 4, seg = t & 15;  // 16 threads/row, 8 cols each
    float part = 0.f;
#pragma unroll
    for (int j = 0; j < 8; j++) {
      const int k = seg * 8 + j;
      part += bf2f(hv2[0][row][k]) * W3[k];
    }
    part += __shfl_down(part, 8, 16);
    part += __shfl_down(part, 4, 16);
    part += __shfl_down(part, 2, 16);
    part += __shfl_down(part, 1, 16);
    if (seg == 0) votes[row] = part + b3[0];
    __syncthreads();
    if (t < 64) {
      float v = (t < 32) ? votes[t] : 0.f;
#pragma unroll
      for (int off = 32; off > 0; off >>= 1) v += __shfl_down(v, off, 64);
      if (t == 0) atomicAdd(&accg[blockIdx.x >> 2], v);
    }
  }

  // ---- last block to finish applies mean + sigmoid (retires k_final) ----
  if (t == 0) {
    __threadfence();  // make our accg add visible before taking a ticket
    last_s = atomicAdd(cnt, 1u);
  }
  __syncthreads();
  if (last_s == 4 * NG - 1) {  // we are block #256 to finish
    __threadfence();  // acquire: order accg reads after observing all tickets
    if (t < NG) {
      float v = __hip_atomic_load(&accg[t], __ATOMIC_ACQUIRE,
                                  __HIP_MEMORY_SCOPE_AGENT);
      float m = v / (float)slice[t];
      out[t] = 1.f / (1.f + __expf(-m));
    }
  }
}

extern "C" void kernel_launch(void* const* d_in, const int* in_sizes, int n_in,
                              void* d_out, int out_size, void* d_ws, size_t ws_size,
                              hipStream_t stream) {
  const float* M_vv = (const float*)d_in[0];
  const float* M_vc = (const float*)d_in[1];
  const float* C = (const float*)d_in[2];
  const int* slice = (const int*)d_in[3];
  const float* vw = (const float*)d_in[4];
  const float* vb = (const float*)d_in[5];
  const float* mW = (const float*)d_in[6];
  const float* mB = (const float*)d_in[7];
  // d_in[8], d_in[9] (mlpV), d_in[14..17] (color LSTM): dead code
  const float* Wih = (const float*)d_in[10];
  const float* Whh = (const float*)d_in[11];
  const float* bih = (const float*)d_in[12];
  const float* bhh = (const float*)d_in[13];
  const float* W1 = (const float*)d_in[18];
  const float* b1 = (const float*)d_in[19];
  const float* W2 = (const float*)d_in[20];
  const float* b2 = (const float*)d_in[21];
  const float* W3 = (const float*)d_in[22];
  const float* b3 = (const float*)d_in[23];
  float* ws = (float*)d_ws;
  float* out = (float*)d_out;

  k_setup<<<CNUM + 1, 128, 0, stream>>>(C, mW, mB, vw, vb, Wih, bih, bhh, ws,
                                        out + NG + (size_t)NVERT * EDIM);
  k_main<<<256, 512, 0, stream>>>(M_vv, M_vc, Wih, Whh, W1, b1, W2, b2, W3, b3,
                                  slice, ws, out);
}

// Round 4
// 504.384 us; speedup vs baseline: 1.0147x; 1.0087x over previous
//
#include <hip/hip_runtime.h>
#include <hip/hip_bf16.h>
#include <stdint.h>

// ---------------------------------------------------------------------------
// GCPNet forward (ALL I/O FLOAT32):
//   - M_vv @ V == rowsum(M_vv) (x) v0           (V is rank-1)
//   - color LSTM / mlpV / x_c are DEAD CODE     (never reach outputs)
//   - vertex LSTM is row-independent            -> persistent per-tile kernel
// R4-R6: full fusion into k_setup + k_main; last-block ticket retires k_final.
// R7: OCCUPANCY ROUND. rocprof showed k_main = 181us @ 826 GB/s (10% peak),
// MfmaUtil 8%, Occupancy 21.7% -> latency-bound, NOT BW-bound. Cause: grid
// 256 = 1 block/CU (8 waves). Restructure: 512 blocks x 16 rows/block
// -> 2 blocks/CU, 16 waves/CU, LDS 60->30KB, VGPR pressure down
// (av[8]->av[4], xg[2][4]->xg[4]); __launch_bounds__(512,4) caps VGPR<=128.
// Two blocks/CU fill each other's barrier bubbles in stream + LSTM phases.
// ---------------------------------------------------------------------------

typedef __bf16 bf16x8 __attribute__((ext_vector_type(8)));
typedef float f32x4 __attribute__((ext_vector_type(4)));

#define EDIM 128
#define NVERT 8192
#define CNUM 512
#define NG 64
#define TSTEPS 32
#define ROWS 16  // rows per block (R7: was 32)

// workspace byte offsets
#define WS_CNT 0u         // 1 u32   (completion ticket counter)
#define WS_V0 32768u      // 128 f32
#define WS_W1 33280u      // 512 f32  (Wih_v[:, :128] @ v0)
#define WS_BV 35328u      // 512 f32  (bih_v + bhh_v)
#define WS_ACC 37376u     // 64 f32   (per-graph vote sums)
#define WS_V0BF 37632u    // 128 bf16
#define WS_MLPC3T 38912u  // 128*512 bf16 (mlp3(C) transposed: [e][c])

__device__ __forceinline__ float bf2f(unsigned short s) {
  return __uint_as_float(((unsigned)s) << 16);
}
__device__ __forceinline__ unsigned short f2bf(float f) {
  unsigned u = __float_as_uint(f);
  u += 0x7fffu + ((u >> 16) & 1u);  // RNE
  return (unsigned short)(u >> 16);
}
__device__ __forceinline__ float sigm(float x) {
  return __builtin_amdgcn_rcpf(1.f + __expf(-x));
}
__device__ __forceinline__ float tanh_f(float x) {
  return 1.f - 2.f * __builtin_amdgcn_rcpf(1.f + __expf(2.f * x));
}
__device__ __forceinline__ f32x4 mfma16(bf16x8 a, bf16x8 b, f32x4 c) {
  return __builtin_amdgcn_mfma_f32_16x16x32_bf16(a, b, c, 0, 0, 0);
}
// load 8 consecutive f32 from global, convert to bf16x8 fragment
__device__ __forceinline__ bf16x8 ld8(const float* p) {
  float4 a = *(const float4*)p;
  float4 b = *(const float4*)(p + 4);
  bf16x8 r;
  r[0] = (__bf16)a.x; r[1] = (__bf16)a.y; r[2] = (__bf16)a.z; r[3] = (__bf16)a.w;
  r[4] = (__bf16)b.x; r[5] = (__bf16)b.y; r[6] = (__bf16)b.z; r[7] = (__bf16)b.w;
  return r;
}

// ---------------- setup: prep (block 512) + mlp3(C) (blocks 0..511) --------
__global__ __launch_bounds__(128) void k_setup(
    const float* __restrict__ C, const float* __restrict__ W,
    const float* __restrict__ B, const float* __restrict__ vw,
    const float* __restrict__ vb, const float* __restrict__ Wih,
    const float* __restrict__ bih, const float* __restrict__ bhh,
    float* __restrict__ ws, float* __restrict__ Cout) {
  __shared__ float xb[2][EDIM];
  const int t = threadIdx.x;

  if (blockIdx.x == CNUM) {
    // ---- prep: v0, w1 = Wih[:, :128] @ v0, bv, zero acc + ticket ----
    float* v0 = (float*)((char*)ws + WS_V0);
    float* w1 = (float*)((char*)ws + WS_W1);
    float* bvp = (float*)((char*)ws + WS_BV);
    float* acc = (float*)((char*)ws + WS_ACC);
    unsigned short* v0bf = (unsigned short*)((char*)ws + WS_V0BF);
    unsigned int* cnt = (unsigned int*)((char*)ws + WS_CNT);
    float v = vw[t] + vb[t];
    xb[0][t] = v;
    v0[t] = v;
    v0bf[t] = f2bf(v);
    if (t < NG) acc[t] = 0.f;
    if (t == 0) *cnt = 0u;
    __syncthreads();
#pragma unroll
    for (int gi = 0; gi < 4; gi++) {
      const int col = gi * EDIM + t;
      const float4* wr = (const float4*)(Wih + (size_t)col * 256);  // left cols
      float s = 0.f;
#pragma unroll
      for (int kc = 0; kc < 32; kc++) {
        float4 q = wr[kc];
        const float* xi = xb[0] + kc * 4;
        s += q.x * xi[0] + q.y * xi[1] + q.z * xi[2] + q.w * xi[3];
      }
      w1[col] = s;
      bvp[col] = bih[col] + bhh[col];
    }
    return;
  }

  // ---- mlp3(C) -> mlpC3^T (bf16) in ws, + C output copy ----
  unsigned short* out_t = (unsigned short*)((char*)ws + WS_MLPC3T);
  const int c = blockIdx.x, e = t;
  float cval = C[c * EDIM + e];
  xb[0][e] = cval;
  Cout[c * EDIM + e] = cval;  // output 3 (exact f32 copy)
  __syncthreads();
#pragma unroll
  for (int l = 0; l < 3; l++) {
    const float4* wrow = (const float4*)(W + ((size_t)l * EDIM + e) * EDIM);
    const float* xin = xb[l & 1];
    float s = B[l * EDIM + e];
#pragma unroll
    for (int kc = 0; kc < EDIM / 4; kc++) {
      float4 q = wrow[kc];
      const float* xi = xin + kc * 4;
      s += q.x * xi[0] + q.y * xi[1] + q.z * xi[2] + q.w * xi[3];
    }
    if (l < 2) {
      s = fmaxf(s, 0.f);
      __syncthreads();
      xb[(l + 1) & 1][e] = s;
      __syncthreads();
    } else {
      out_t[(size_t)e * CNUM + c] = f2bf(s);  // transposed for MFMA B reads
    }
  }
}

// ---------------- fused rowsum + LSTM + vote + final (512 x 512) -----------
// 8 waves/block; wave w owns cols [16w, 16w+16) of the 128-wide hidden dim.
// Each block owns 16 vertex rows; 2 blocks resident per CU.
__global__ __launch_bounds__(512, 4) void k_main(
    const float* __restrict__ Mvv, const float* __restrict__ Mvc,
    const float* __restrict__ Wih, const float* __restrict__ Whh,
    const float* __restrict__ W1, const float* __restrict__ b1,
    const float* __restrict__ W2, const float* __restrict__ b2,
    const float* __restrict__ W3, const float* __restrict__ b3,
    const int* __restrict__ slice, float* __restrict__ ws,
    float* __restrict__ out) {
  const int r0 = blockIdx.x * ROWS;
  const int t = threadIdx.x;
  const int w = t >> 6;
  const int lane = t & 63;
  const int quad = lane >> 4;
  const int l15 = lane & 15;
  const int nc0 = w * 16;  // wave's 16-col slice of 128

  __shared__ unsigned short Avc[ROWS][CNUM + 8];     // M_vc tile (bf16)
  __shared__ unsigned short Tt[ROWS][EDIM + 8];      // T = M_vc @ mlpC3
  __shared__ unsigned short hv2[2][ROWS][EDIM + 8];  // double-buffered hidden
  __shared__ float votes[ROWS];
  __shared__ float rs_s[ROWS];                       // rowsums of block's rows
  __shared__ unsigned int last_s;

  const float* w1v = (const float*)((const char*)ws + WS_W1);
  const float* bvv = (const float*)((const char*)ws + WS_BV);
  float* accg = (float*)((char*)ws + WS_ACC);
  unsigned int* cnt = (unsigned int*)((char*)ws + WS_CNT);
  const unsigned short* v0bf = (const unsigned short*)((const char*)ws + WS_V0BF);
  const unsigned short* m3t = (const unsigned short*)((const char*)ws + WS_MLPC3T);

  // ---- phase 1: issue M_vc tile loads, stream-rowsum own 16 M_vv rows ----
  {
    const int row = t >> 5, c0 = t & 31;  // 32 threads/row
    // issue M_vc loads early (they drain under the M_vv stream)
    // 16 rows x 128 float4 = 2048 float4 -> 4 per thread
    const float4* g = (const float4*)(Mvc + (size_t)(r0 + row) * CNUM);
    float4 av[4];
#pragma unroll
    for (int it = 0; it < 4; it++) av[it] = g[it * 32 + c0];

    // rowsum: 2048 float4/row, 32 threads/row -> 64 float4/thread,
    // chunked 16-deep for vmem pipelining
    const float4* mp = (const float4*)(Mvv + (size_t)(r0 + row) * NVERT) + c0;
    float s = 0.f;
#pragma unroll 1
    for (int ch = 0; ch < 4; ch++) {
      float4 q[16];
#pragma unroll
      for (int j = 0; j < 16; j++) q[j] = mp[ch * 512 + j * 32];
#pragma unroll
      for (int j = 0; j < 16; j++) s += q[j].x + q[j].y + q[j].z + q[j].w;
    }
    s += __shfl_down(s, 16, 32);
    s += __shfl_down(s, 8, 32);
    s += __shfl_down(s, 4, 32);
    s += __shfl_down(s, 2, 32);
    s += __shfl_down(s, 1, 32);
    if (c0 == 0) rs_s[row] = s;

    // now convert the (long-drained) M_vc tile to bf16 in LDS
#pragma unroll
    for (int it = 0; it < 4; it++) {
      int c4 = it * 32 + c0;
      ushort4 h;
      h.x = f2bf(av[it].x); h.y = f2bf(av[it].y);
      h.z = f2bf(av[it].z); h.w = f2bf(av[it].w);
      *(ushort4*)&Avc[row][c4 * 4] = h;
    }
  }
  // output 2: V rows = v0 (exact f32): 16 rows x 32 float4 = 512 = 1 pass
  {
    const float4* v04 = (const float4*)((const char*)ws + WS_V0);
    float4* V4 = (float4*)(out + NG);
    int vr = t >> 5, vc = t & 31;
    V4[(size_t)(r0 + vr) * 32 + vc] = v04[vc];
  }
  // init hv = v0 (bf16): 16*128 = 2048 ushort
  for (int i = t; i < ROWS * EDIM; i += 512) hv2[0][i >> 7][i & 127] = v0bf[i & 127];
  __syncthreads();

  // ---- T = Avc @ mlpC3 (B from transposed mlpC3: contiguous in k) ----
  {
    f32x4 acc;
    acc[0] = 0.f; acc[1] = 0.f; acc[2] = 0.f; acc[3] = 0.f;
#pragma unroll
    for (int kc = 0; kc < 16; kc++) {
      bf16x8 a0 = *(const bf16x8*)&Avc[l15][kc * 32 + quad * 8];
      bf16x8 b0 = *(const bf16x8*)&m3t[(size_t)(nc0 + l15) * CNUM + kc * 32 + quad * 8];
      acc = mfma16(a0, b0, acc);
    }
#pragma unroll
    for (int r = 0; r < 4; r++)
      Tt[quad * 4 + r][nc0 + l15] = f2bf(acc[r]);
  }
  __syncthreads();

  // ---- xg = x_v @ Wih^T + bih + bhh (loop-invariant gate preactivation) ----
  // left half of x_v is rs[i]*v0[e] -> contributes rs[i]*w1[g]
  f32x4 xg[4];  // [gate i,f,g,o]
  {
    float rsv[4];
#pragma unroll
    for (int r = 0; r < 4; r++) rsv[r] = rs_s[quad * 4 + r];
#pragma unroll
    for (int gi = 0; gi < 4; gi++) {
      const int col = gi * 128 + nc0 + l15;
      const float w1c = w1v[col], bvc = bvv[col];
#pragma unroll
      for (int r = 0; r < 4; r++) xg[gi][r] = fmaf(rsv[r], w1c, bvc);
    }
#pragma unroll
    for (int kc = 0; kc < 4; kc++) {
      bf16x8 a0 = *(const bf16x8*)&Tt[l15][kc * 32 + quad * 8];
#pragma unroll
      for (int gi = 0; gi < 4; gi++) {
        const int gcol = gi * 128 + nc0 + l15;
        bf16x8 bfr = ld8(&Wih[(size_t)gcol * 256 + 128 + kc * 32 + quad * 8]);
        xg[gi] = mfma16(a0, bfr, xg[gi]);
      }
    }
  }

  // Whh B-fragments held in registers for all 32 steps (64 VGPR)
  bf16x8 Bh[4][4];
#pragma unroll
  for (int gi = 0; gi < 4; gi++) {
    const int gcol = gi * 128 + nc0 + l15;
#pragma unroll
    for (int kc = 0; kc < 4; kc++)
      Bh[gi][kc] = ld8(&Whh[(size_t)gcol * EDIM + kc * 32 + quad * 8]);
  }

  f32x4 cv;
  cv[0] = 0.f; cv[1] = 0.f; cv[2] = 0.f; cv[3] = 0.f;

  // ---- 32 LSTM steps; read buf p, write buf p^1, ONE barrier/step ----
  int p = 0;
#pragma unroll 1
  for (int step = 0; step < TSTEPS; step++) {
    bf16x8 A[4];
#pragma unroll
    for (int kc = 0; kc < 4; kc++)
      A[kc] = *(const bf16x8*)&hv2[p][l15][kc * 32 + quad * 8];
    f32x4 gI = xg[0], gF = xg[1], gG = xg[2], gO = xg[3];
#pragma unroll
    for (int kc = 0; kc < 4; kc++) {
      gI = mfma16(A[kc], Bh[0][kc], gI);
      gF = mfma16(A[kc], Bh[1][kc], gF);
      gG = mfma16(A[kc], Bh[2][kc], gG);
      gO = mfma16(A[kc], Bh[3][kc], gO);
    }
#pragma unroll
    for (int r = 0; r < 4; r++) {
      float ig = sigm(gI[r]), fg = sigm(gF[r]);
      float gg = tanh_f(gG[r]), og = sigm(gO[r]);
      float c2 = fmaf(fg, cv[r], ig * gg);
      cv[r] = c2;
      hv2[p ^ 1][quad * 4 + r][nc0 + l15] = f2bf(og * tanh_f(c2));
    }
    p ^= 1;
    __syncthreads();
  }
  // after 32 steps (even), final h is in hv2[0]

  // ---- fused vote MLP: two relu layers via MFMA ----
  for (int layer = 0; layer < 2; layer++) {
    const float* Wg = layer ? W2 : W1;
    const float* bg = layer ? b2 : b1;
    bf16x8 A[4];
#pragma unroll
    for (int kc = 0; kc < 4; kc++)
      A[kc] = *(const bf16x8*)&hv2[0][l15][kc * 32 + quad * 8];
    f32x4 acc;
    {
      float bb = bg[nc0 + l15];
      acc[0] = bb; acc[1] = bb; acc[2] = bb; acc[3] = bb;
    }
#pragma unroll
    for (int kc = 0; kc < 4; kc++) {
      bf16x8 bfr = ld8(&Wg[(size_t)(nc0 + l15) * EDIM + kc * 32 + quad * 8]);
      acc = mfma16(A[kc], bfr, acc);
    }
    __syncthreads();  // all A reads done before overwrite
#pragma unroll
    for (int r = 0; r < 4; r++)
      hv2[0][quad * 4 + r][nc0 + l15] = f2bf(fmaxf(acc[r], 0.f));
    __syncthreads();
  }

  // final vote row-dot + per-graph partial sum (block is inside one graph)
  {
    if (t < 16 * ROWS) {
      const int row = t >> 4, seg = t & 15;  // 16 threads/row, 8 cols each
      float part = 0.f;
#pragma unroll
      for (int j = 0; j < 8; j++) {
        const int k = seg * 8 + j;
        part += bf2f(hv2[0][row][k]) * W3[k];
      }
      part += __shfl_down(part, 8, 16);
      part += __shfl_down(part, 4, 16);
      part += __shfl_down(part, 2, 16);
      part += __shfl_down(part, 1, 16);
      if (seg == 0) votes[row] = part + b3[0];
    }
    __syncthreads();
    if (t < 64) {
      float v = (t < ROWS) ? votes[t] : 0.f;
#pragma unroll
      for (int off = 32; off > 0; off >>= 1) v += __shfl_down(v, off, 64);
      if (t == 0) atomicAdd(&accg[blockIdx.x >> 3], v);
    }
  }

  // ---- last block to finish applies mean + sigmoid (retires k_final) ----
  if (t == 0) {
    __threadfence();  // make our accg add visible before taking a ticket
    last_s = atomicAdd(cnt, 1u);
  }
  __syncthreads();
  if (last_s == 8 * NG - 1) {  // we are block #512 to finish
    __threadfence();  // acquire: order accg reads after observing all tickets
    if (t < NG) {
      float v = __hip_atomic_load(&accg[t], __ATOMIC_ACQUIRE,
                                  __HIP_MEMORY_SCOPE_AGENT);
      float m = v / (float)slice[t];
      out[t] = 1.f / (1.f + __expf(-m));
    }
  }
}

extern "C" void kernel_launch(void* const* d_in, const int* in_sizes, int n_in,
                              void* d_out, int out_size, void* d_ws, size_t ws_size,
                              hipStream_t stream) {
  const float* M_vv = (const float*)d_in[0];
  const float* M_vc = (const float*)d_in[1];
  const float* C = (const float*)d_in[2];
  const int* slice = (const int*)d_in[3];
  const float* vw = (const float*)d_in[4];
  const float* vb = (const float*)d_in[5];
  const float* mW = (const float*)d_in[6];
  const float* mB = (const float*)d_in[7];
  // d_in[8], d_in[9] (mlpV), d_in[14..17] (color LSTM): dead code
  const float* Wih = (const float*)d_in[10];
  const float* Whh = (const float*)d_in[11];
  const float* bih = (const float*)d_in[12];
  const float* bhh = (const float*)d_in[13];
  const float* W1 = (const float*)d_in[18];
  const float* b1 = (const float*)d_in[19];
  const float* W2 = (const float*)d_in[20];
  const float* b2 = (const float*)d_in[21];
  const float* W3 = (const float*)d_in[22];
  const float* b3 = (const float*)d_in[23];
  float* ws = (float*)d_ws;
  float* out = (float*)d_out;

  k_setup<<<CNUM + 1, 128, 0, stream>>>(C, mW, mB, vw, vb, Wih, bih, bhh, ws,
                                        out + NG + (size_t)NVERT * EDIM);
  k_main<<<NVERT / ROWS, 512, 0, stream>>>(M_vv, M_vc, Wih, Whh, W1, b1, W2,
                                           b2, W3, b3, slice, ws, out);
}